// Round 7
// baseline (444.372 us; speedup 1.0000x reference)
//
#include <hip/hip_runtime.h>
#include <cstddef>

#define B_  64
#define D_  128
#define LC_ 1000
#define LQ_ 100
#define SP  104   // S row stride (padded LQ, mult of 8)
#define JP  128   // cm/cs stride

// ---------------- K0: transpose C (B,D,LC) -> Ct (B,LC,D) ----------------
__global__ __launch_bounds__(256) void k_transpose(const float* __restrict__ C,
                                                   float* __restrict__ Ct){
  __shared__ float t[32][33];
  int b  = blockIdx.z;
  int i0 = blockIdx.x * 32;
  int d0 = blockIdx.y * 32;
  int tx = threadIdx.x, ty = threadIdx.y;
  const float* Cb  = C  + (size_t)b * D_ * LC_;
  float*       Ctb = Ct + (size_t)b * LC_ * D_;
#pragma unroll
  for(int k=0;k<4;k++){
    int d = d0 + ty + 8*k;
    int i = i0 + tx;
    t[ty+8*k][tx] = (i < LC_) ? Cb[(size_t)d*LC_ + i] : 0.f;
  }
  __syncthreads();
#pragma unroll
  for(int k=0;k<4;k++){
    int i = i0 + ty + 8*k;
    int d = d0 + tx;
    if(i < LC_) Ctb[(size_t)i*D_ + d] = t[tx][ty+8*k];
  }
}

// ---------------- K0b: transpose Q (B,D,LQ) -> Qt (B,LQ,D) ----------------
__global__ __launch_bounds__(256) void k_transposeQ(const float* __restrict__ Q,
                                                    float* __restrict__ Qt){
  __shared__ float t[32][33];
  int b  = blockIdx.z;
  int j0 = blockIdx.x * 32;
  int d0 = blockIdx.y * 32;
  int tx = threadIdx.x, ty = threadIdx.y;
  const float* Qb  = Q  + (size_t)b * D_ * LQ_;
  float*       Qtb = Qt + (size_t)b * LQ_ * D_;
#pragma unroll
  for(int k=0;k<4;k++){
    int d = d0 + ty + 8*k;
    int j = j0 + tx;
    t[ty+8*k][tx] = (j < LQ_) ? Qb[(size_t)d*LQ_ + j] : 0.f;
  }
  __syncthreads();
#pragma unroll
  for(int k=0;k<4;k++){
    int j = j0 + ty + 8*k;
    int d = d0 + tx;
    if(j < LQ_) Qtb[(size_t)j*D_ + d] = t[tx][ty+8*k];
  }
}

// ---------------- K1: S[b,i,j] = sum_d (w1+w3*Ct)[i,d]*Q[d,j] + t2[i] ----------------
__global__ __launch_bounds__(256) void k_S(const float* __restrict__ Q,
                                           const float* __restrict__ W,
                                           const float* __restrict__ Ct,
                                           float* __restrict__ S){
  __shared__ float Qs[32][132];
  __shared__ float Vs[32][68];    // [dc][il] transposed: inner loop reads b128
  __shared__ float t2s[64];
  int b   = blockIdx.y;
  int i0  = blockIdx.x * 64;
  int tid = threadIdx.x;
  const float* Wb  = W  + (size_t)b * LC_ * 384;
  const float* Ctb = Ct + (size_t)b * LC_ * D_;
  const float* Qb  = Q  + (size_t)b * D_ * LQ_;

  // t2[i] = sum_d w2[i,d]*Ct[i,d]
  {
    int g = tid >> 5, l = tid & 31;
    for(int rep=0; rep<8; rep++){
      int il = rep*8 + g;
      int i  = i0 + il;
      float s = 0.f;
      if(i < LC_){
        const float* wrow  = Wb  + (size_t)i*384 + 128;
        const float* ctrow = Ctb + (size_t)i*D_;
#pragma unroll
        for(int k=0;k<4;k++){ int d = l + 32*k; s += wrow[d]*ctrow[d]; }
      }
#pragma unroll
      for(int m=16;m>0;m>>=1) s += __shfl_xor(s, m, 64);
      if(l==0) t2s[il] = s;
    }
  }

  int jt = tid & 15;
  int ti = tid >> 4;
  float acc[4][8] = {};

  for(int c=0;c<4;c++){
    int dc0 = c*32;
    __syncthreads();
    for(int idx=tid; idx<32*128; idx+=256){
      int dc = idx >> 7, j = idx & 127;
      Qs[dc][j] = (j < LQ_) ? Qb[(size_t)(dc0+dc)*LQ_ + j] : 0.f;
    }
    for(int idx=tid; idx<64*32; idx+=256){
      int il = idx >> 5, dc = idx & 31;
      int i = i0 + il;
      float v = 0.f;
      if(i < LC_){
        const float* wrow = Wb + (size_t)i*384;
        float ct = Ctb[(size_t)i*D_ + dc0+dc];
        v = wrow[dc0+dc] + wrow[256+dc0+dc]*ct;
      }
      Vs[dc][il] = v;
    }
    __syncthreads();
#pragma unroll 4
    for(int dc=0; dc<32; dc++){
      float4 vv = *(const float4*)&Vs[dc][ti*4];
      float v[4] = {vv.x, vv.y, vv.z, vv.w};
      float4 q0 = *(const float4*)&Qs[dc][jt*8];
      float4 q1 = *(const float4*)&Qs[dc][jt*8+4];
      float q[8] = {q0.x,q0.y,q0.z,q0.w,q1.x,q1.y,q1.z,q1.w};
#pragma unroll
      for(int ii=0; ii<4; ii++)
#pragma unroll
        for(int jj=0; jj<8; jj++) acc[ii][jj] += v[ii]*q[jj];
    }
  }
  float* Sb = S + (size_t)b * LC_ * SP;
#pragma unroll
  for(int ii=0; ii<4; ii++){
    int il = ti*4+ii;
    int i  = i0 + il;
    if(i < LC_){
      float t2v = t2s[il];
      float4 o0, o1;
      o0.x=acc[ii][0]+t2v; o0.y=acc[ii][1]+t2v; o0.z=acc[ii][2]+t2v; o0.w=acc[ii][3]+t2v;
      o1.x=acc[ii][4]+t2v; o1.y=acc[ii][5]+t2v; o1.z=acc[ii][6]+t2v; o1.w=acc[ii][7]+t2v;
      if(jt*8   < SP) *(float4*)&Sb[(size_t)i*SP + jt*8    ] = o0;  // j<104 only
      if(jt*8+4 < SP) *(float4*)&Sb[(size_t)i*SP + jt*8 + 4] = o1;
    }
  }
}

// ---------------- K2a: partial column stats (softmax axis=1) ----------------
#define NIC 8
__global__ __launch_bounds__(256) void k_colstats1(const float* __restrict__ S,
                                                   float* __restrict__ pm,
                                                   float* __restrict__ ps){
  __shared__ float lm[8][128], lsum[8][128];
  int b = blockIdx.x, ic = blockIdx.y;
  int tid = threadIdx.x;
  int jt = tid & 31, h = tid >> 5;
  int j0 = jt*4;
  int ni = min(16, 125 - h*16);
  const float* Sb = S + (size_t)b * LC_ * SP;
  float m[4] = {-1e30f,-1e30f,-1e30f,-1e30f}, s[4] = {0.f,0.f,0.f,0.f};
  if(jt < 26){
    for(int r=0;r<ni;r++){
      int i = ic*125 + h*16 + r;
      float4 x = *(const float4*)&Sb[(size_t)i*SP + j0];
      float xv[4] = {x.x,x.y,x.z,x.w};
#pragma unroll
      for(int k=0;k<4;k++){
        if(xv[k] > m[k]){ s[k] = s[k]*__expf(m[k]-xv[k]) + 1.f; m[k] = xv[k]; }
        else              s[k] += __expf(xv[k]-m[k]);
      }
    }
  }
#pragma unroll
  for(int k=0;k<4;k++){
    int j = j0+k;
    if(j < 128){ lm[h][j] = m[k]; lsum[h][j] = s[k]; }
  }
  __syncthreads();
  if(tid < 128){
    float mm = -1e30f, ss = 0.f;
#pragma unroll
    for(int hh=0; hh<8; hh++){
      float m2 = lm[hh][tid], s2 = lsum[hh][tid];
      if(m2 > mm){ ss = ss*__expf(mm-m2) + s2; mm = m2; }
      else         ss += s2*__expf(m2-mm);
    }
    pm[((size_t)b*NIC + ic)*128 + tid] = mm;
    ps[((size_t)b*NIC + ic)*128 + tid] = ss;
  }
}

// ---------------- K2b: combine partials ----------------
__global__ __launch_bounds__(128) void k_colstats2(const float* __restrict__ pm,
                                                   const float* __restrict__ ps,
                                                   float* __restrict__ cm,
                                                   float* __restrict__ cs){
  int b = blockIdx.x, j = threadIdx.x;
  float mm = -1e30f, ss = 0.f;
#pragma unroll
  for(int ic=0; ic<NIC; ic++){
    float m2 = pm[((size_t)b*NIC + ic)*128 + j];
    float s2 = ps[((size_t)b*NIC + ic)*128 + j];
    if(m2 > mm){ ss = ss*__expf(mm-m2) + s2; mm = m2; }
    else         ss += s2*__expf(m2-mm);
  }
  cm[b*JP + j] = mm;
  cs[b*JP + j] = (ss == 0.f) ? 1.f : ss;
}

// ---------------- K3: M[b,j,d] = sum_i softmax_col(S)[i,j]*Ct[i,d] ----------------
#define MJQ 25
__global__ __launch_bounds__(1024) void k_Mj(const float* __restrict__ S,
                                             const float* __restrict__ Ct,
                                             const float* __restrict__ cm_,
                                             const float* __restrict__ cs_,
                                             float* __restrict__ M){
  __shared__ float Es[4][16][32];    // [grp][i-chunk][j_local]
  __shared__ float Cs[4][16][132];   // [grp][i-chunk][d]
  __shared__ float Macc[25][132];    // cross-group accumulation tile
  __shared__ float cml[32], icsl[32];
  int b  = blockIdx.x;
  int jq = blockIdx.y;
  int j0 = jq * MJQ;
  int tid = threadIdx.x;             // 0..1023
  int grp = tid >> 8;                // 0..3 (i-range group)
  int t   = tid & 255;
  if(tid < 32){
    int j = j0 + tid;
    cml[tid]  = (tid < MJQ && j < LQ_) ? cm_[b*JP + j] : 0.f;
    icsl[tid] = (tid < MJQ && j < LQ_) ? 1.f/cs_[b*JP + j] : 0.f;
  }
  __syncthreads();
  int dt = t & 31;   // d = dt*4 + dd
  int jt = t >> 5;   // j_local = jt*4 + jj (0..31, mask < MJQ)
  float acc[4][4] = {};
  const float* Sb  = S  + (size_t)b * LC_ * SP + j0;
  const float* Ctb = Ct + (size_t)b * LC_ * D_;
  int ibase = grp * 250;

  for(int i0=0; i0<250; i0+=16){
    int rem = min(16, 250 - i0);
    __syncthreads();
    for(int idx=t; idx<16*32; idx+=256){
      int ii = idx >> 5, jl = idx & 31;
      float e = 0.f;
      if(ii < rem && jl < MJQ)
        e = __expf(Sb[(size_t)(ibase+i0+ii)*SP + jl] - cml[jl]);
      Es[grp][ii][jl] = e;
    }
    for(int idx=t; idx<16*32; idx+=256){
      int ii = idx >> 5, f = idx & 31;
      float4 v = make_float4(0.f,0.f,0.f,0.f);
      if(ii < rem) v = *(const float4*)&Ctb[(size_t)(ibase+i0+ii)*D_ + f*4];
      *(float4*)&Cs[grp][ii][f*4] = v;
    }
    __syncthreads();
#pragma unroll
    for(int ii=0; ii<16; ii++){
      float4 e4 = *(const float4*)&Es[grp][ii][jt*4];
      float4 c4 = *(const float4*)&Cs[grp][ii][dt*4];
      float e[4] = {e4.x,e4.y,e4.z,e4.w};
      float c[4] = {c4.x,c4.y,c4.z,c4.w};
#pragma unroll
      for(int jj=0; jj<4; jj++)
#pragma unroll
        for(int dd=0; dd<4; dd++) acc[jj][dd] += e[jj]*c[dd];
    }
  }

  // cross-group reduce (turn-taking; deterministic)
  for(int g=0; g<4; g++){
    if(grp == g){
#pragma unroll
      for(int jj=0; jj<4; jj++){
        int jl = jt*4 + jj;
        if(jl < MJQ){
#pragma unroll
          for(int dd=0; dd<4; dd++){
            if(g == 0) Macc[jl][dt*4+dd]  = acc[jj][dd];
            else       Macc[jl][dt*4+dd] += acc[jj][dd];
          }
        }
      }
    }
    __syncthreads();
  }
  if(grp == 0){
    float* Mb = M + (size_t)b * JP * D_;
#pragma unroll
    for(int jj=0; jj<4; jj++){
      int jl = jt*4 + jj;
      if(jl < MJQ && (j0+jl) < LQ_){
        float ics = icsl[jl];
        float4 o;
        o.x = Macc[jl][dt*4+0]*ics; o.y = Macc[jl][dt*4+1]*ics;
        o.z = Macc[jl][dt*4+2]*ics; o.w = Macc[jl][dt*4+3]*ics;
        *(float4*)&Mb[(size_t)(j0+jl)*D_ + dt*4] = o;
      }
    }
  }
}

// ---------------- K4: row softmax + A=S1@Qt + Bm=S1@M + assemble output ----------------
// T14 async-stage: next j-chunk's Qt/M loads issued into regs before the GEMM,
// LDS-written after the post-GEMM barrier (HBM latency hides under FMA).
__global__ __launch_bounds__(256) void k_final(const float* __restrict__ S,
                                               const float* __restrict__ Qt,
                                               const float* __restrict__ M,
                                               const float* __restrict__ C,
                                               float* __restrict__ out){
  __shared__ float lds[10880];
  float* S1s = lds;            // [64][104]
  float* Qc  = lds + 6656;     // [16][132]
  float* Mc  = lds + 8768;     // [16][132]
  float* At  = lds;            // [64][133] epilogue transpose (reuse)
  int b   = blockIdx.y;
  int i0  = blockIdx.x * 64;
  int tid = threadIdx.x;
  const float* Sb  = S  + (size_t)b * LC_ * SP;
  const float* Qtb = Qt + (size_t)b * LQ_ * D_;
  const float* Mb  = M  + (size_t)b * JP * D_;

  float4 pq[2], pmr[2];
  auto pfload = [&](int j0c){
    int nj = min(16, LQ_-j0c);
#pragma unroll
    for(int k=0;k<2;k++){
      int idx = tid + k*256;
      int jj = idx >> 5, f = idx & 31;
      if(jj < nj){
        pq[k]  = *(const float4*)&Qtb[(size_t)(j0c+jj)*D_ + f*4];
        pmr[k] = *(const float4*)&Mb [(size_t)(j0c+jj)*D_ + f*4];
      }
    }
  };
  auto pfstore = [&](int j0c){
    int nj = min(16, LQ_-j0c);
#pragma unroll
    for(int k=0;k<2;k++){
      int idx = tid + k*256;
      int jj = idx >> 5, f = idx & 31;
      if(jj < nj){
        *(float4*)&Qc[jj*132 + f*4] = pq[k];
        *(float4*)&Mc[jj*132 + f*4] = pmr[k];
      }
    }
  };

  // stage S tile (zero cols 100..103)
  for(int idx=tid; idx<64*26; idx+=256){
    int il = idx / 26, f = idx % 26;
    int i = i0 + il;
    float4 v = make_float4(0.f,0.f,0.f,0.f);
    if(i < LC_ && f < 25) v = *(const float4*)&Sb[(size_t)i*SP + f*4];
    *(float4*)&S1s[il*104 + f*4] = v;
  }
  pfload(0);
  __syncthreads();

  // in-LDS row softmax over j<100 (4 waves x 16 rows, 2 cols/lane)
  {
    int w = tid >> 6, l = tid & 63;
    for(int r=0; r<16; r++){
      int il = w*16 + r;
      float x0 = (2*l   < LQ_) ? S1s[il*104 + 2*l  ] : -1e30f;
      float x1 = (2*l+1 < LQ_) ? S1s[il*104 + 2*l+1] : -1e30f;
      float m = fmaxf(x0,x1);
#pragma unroll
      for(int mm=32;mm>0;mm>>=1) m = fmaxf(m, __shfl_xor(m, mm, 64));
      float e0 = (2*l   < LQ_) ? __expf(x0-m) : 0.f;
      float e1 = (2*l+1 < LQ_) ? __expf(x1-m) : 0.f;
      float s = e0+e1;
#pragma unroll
      for(int mm=32;mm>0;mm>>=1) s += __shfl_xor(s, mm, 64);
      float inv = 1.f/s;
      if(2*l   < LQ_) S1s[il*104 + 2*l  ] = e0*inv;
      if(2*l+1 < LQ_) S1s[il*104 + 2*l+1] = e1*inv;
    }
  }
  pfstore(0);
  pfload(16);
  __syncthreads();

  int dt = tid & 31;
  int it = tid >> 5;
  float A[8][4] = {}, Bm[8][4] = {};
  for(int j0=0; j0<LQ_; j0+=16){
    int nj = min(16, LQ_-j0);
    for(int jj4=0; jj4<nj; jj4+=4){
      float4 sv[8], qv[4], mv[4];
#pragma unroll
      for(int ii=0; ii<8; ii++) sv[ii] = *(const float4*)&S1s[(it*8+ii)*104 + j0+jj4];
#pragma unroll
      for(int jj=0; jj<4; jj++){
        qv[jj] = *(const float4*)&Qc[(jj4+jj)*132 + dt*4];
        mv[jj] = *(const float4*)&Mc[(jj4+jj)*132 + dt*4];
      }
#pragma unroll
      for(int ii=0; ii<8; ii++){
        float sf[4] = {sv[ii].x, sv[ii].y, sv[ii].z, sv[ii].w};
#pragma unroll
        for(int jj=0; jj<4; jj++){
          A[ii][0]  += sf[jj]*qv[jj].x; A[ii][1]  += sf[jj]*qv[jj].y;
          A[ii][2]  += sf[jj]*qv[jj].z; A[ii][3]  += sf[jj]*qv[jj].w;
          Bm[ii][0] += sf[jj]*mv[jj].x; Bm[ii][1] += sf[jj]*mv[jj].y;
          Bm[ii][2] += sf[jj]*mv[jj].z; Bm[ii][3] += sf[jj]*mv[jj].w;
        }
      }
    }
    __syncthreads();
    if(j0+16 < LQ_){
      pfstore(j0+16);
      if(j0+32 < LQ_) pfload(j0+32);
      __syncthreads();
    }
  }

  // epilogue: LDS round-trip (At stride 133), float4-along-i reads of C and
  // float4 stores. thread = (iq = tid&15, dbase = tid>>4), d = dbase+16*m.
  // At-read banks: (20*iq + 5*r + dbase + 16*m) mod 32 -> exact 2-way (free).
  const float* Cb = C + (size_t)b * D_ * LC_;
  float* ob = out + (size_t)b * 512 * LC_;
  int iq = tid & 15, dbase = tid >> 4;
  int i  = i0 + iq*4;
  bool iok = (i + 3) < LC_;   // LC_=1000 is a multiple of 4: exact

#pragma unroll
  for(int ii=0; ii<8; ii++)
#pragma unroll
    for(int dd=0; dd<4; dd++) At[(it*8+ii)*133 + dt*4+dd] = A[ii][dd];
  __syncthreads();
  if(iok){
#pragma unroll
    for(int m=0; m<8; m++){
      int d = dbase + 16*m;
      float4 a;
      a.x = At[(iq*4+0)*133 + d]; a.y = At[(iq*4+1)*133 + d];
      a.z = At[(iq*4+2)*133 + d]; a.w = At[(iq*4+3)*133 + d];
      float4 c = *(const float4*)&Cb[(size_t)d*LC_ + i];
      float4 ca; ca.x=c.x*a.x; ca.y=c.y*a.y; ca.z=c.z*a.z; ca.w=c.w*a.w;
      *(float4*)&ob[(size_t)d*LC_ + i]        = c;
      *(float4*)&ob[(size_t)(128+d)*LC_ + i]  = a;
      *(float4*)&ob[(size_t)(256+d)*LC_ + i]  = ca;
    }
  }
  __syncthreads();
#pragma unroll
  for(int ii=0; ii<8; ii++)
#pragma unroll
    for(int dd=0; dd<4; dd++) At[(it*8+ii)*133 + dt*4+dd] = Bm[ii][dd];
  __syncthreads();
  if(iok){
#pragma unroll
    for(int m=0; m<8; m++){
      int d = dbase + 16*m;
      float4 bm;
      bm.x = At[(iq*4+0)*133 + d]; bm.y = At[(iq*4+1)*133 + d];
      bm.z = At[(iq*4+2)*133 + d]; bm.w = At[(iq*4+3)*133 + d];
      float4 c = *(const float4*)&Cb[(size_t)d*LC_ + i];
      float4 cb; cb.x=c.x*bm.x; cb.y=c.y*bm.y; cb.z=c.z*bm.z; cb.w=c.w*bm.w;
      *(float4*)&ob[(size_t)(384+d)*LC_ + i]  = cb;
    }
  }
}

extern "C" void kernel_launch(void* const* d_in, const int* in_sizes, int n_in,
                              void* d_out, int out_size, void* d_ws, size_t ws_size,
                              hipStream_t stream){
  const float* C = (const float*)d_in[0];
  const float* Q = (const float*)d_in[1];
  const float* W = (const float*)d_in[2];
  float* out = (float*)d_out;
  float* ws  = (float*)d_ws;
  // ws layout (floats): S 6.656M | Ct 8.192M | M 1.049M | Qt 0.819M | pm/ps 65.5K*2 | cm/cs 8.2K*2 = 67.5 MB
  float* S  = ws;
  float* Ct = ws + 6656000;
  float* M  = ws + 14848000;
  float* Qt = ws + 15896576;
  float* pm = ws + 16715776;
  float* ps = ws + 16781312;
  float* cm = ws + 16846848;
  float* cs = ws + 16855040;

  k_transpose <<<dim3(32,4,64), dim3(32,8), 0, stream>>>(C, Ct);
  k_transposeQ<<<dim3(4,4,64),  dim3(32,8), 0, stream>>>(Q, Qt);
  k_S         <<<dim3(16,64),   256, 0, stream>>>(Q, W, Ct, S);
  k_colstats1 <<<dim3(64,NIC),  256, 0, stream>>>(S, pm, ps);
  k_colstats2 <<<64,            128, 0, stream>>>(pm, ps, cm, cs);
  k_Mj        <<<dim3(64,4),    1024, 0, stream>>>(S, Ct, cm, cs, M);
  k_final     <<<dim3(16,64),   256, 0, stream>>>(S, Qt, M, C, out);
}

// Round 8
// 432.432 us; speedup vs baseline: 1.0276x; 1.0276x over previous
//
#include <hip/hip_runtime.h>
#include <cstddef>

#define B_  64
#define D_  128
#define LC_ 1000
#define LQ_ 100
#define SP  104   // S row stride (padded LQ, mult of 8)
#define JP  128   // cm/cs stride

// ---------------- K0: transpose C (B,D,LC) -> Ct (B,LC,D) ----------------
__global__ __launch_bounds__(256) void k_transpose(const float* __restrict__ C,
                                                   float* __restrict__ Ct){
  __shared__ float t[32][33];
  int b  = blockIdx.z;
  int i0 = blockIdx.x * 32;
  int d0 = blockIdx.y * 32;
  int tx = threadIdx.x, ty = threadIdx.y;
  const float* Cb  = C  + (size_t)b * D_ * LC_;
  float*       Ctb = Ct + (size_t)b * LC_ * D_;
#pragma unroll
  for(int k=0;k<4;k++){
    int d = d0 + ty + 8*k;
    int i = i0 + tx;
    t[ty+8*k][tx] = (i < LC_) ? Cb[(size_t)d*LC_ + i] : 0.f;
  }
  __syncthreads();
#pragma unroll
  for(int k=0;k<4;k++){
    int i = i0 + ty + 8*k;
    int d = d0 + tx;
    if(i < LC_) Ctb[(size_t)i*D_ + d] = t[tx][ty+8*k];
  }
}

// ---------------- K0b: transpose Q (B,D,LQ) -> Qt (B,LQ,D) ----------------
__global__ __launch_bounds__(256) void k_transposeQ(const float* __restrict__ Q,
                                                    float* __restrict__ Qt){
  __shared__ float t[32][33];
  int b  = blockIdx.z;
  int j0 = blockIdx.x * 32;
  int d0 = blockIdx.y * 32;
  int tx = threadIdx.x, ty = threadIdx.y;
  const float* Qb  = Q  + (size_t)b * D_ * LQ_;
  float*       Qtb = Qt + (size_t)b * LQ_ * D_;
#pragma unroll
  for(int k=0;k<4;k++){
    int d = d0 + ty + 8*k;
    int j = j0 + tx;
    t[ty+8*k][tx] = (j < LQ_) ? Qb[(size_t)d*LQ_ + j] : 0.f;
  }
  __syncthreads();
#pragma unroll
  for(int k=0;k<4;k++){
    int j = j0 + ty + 8*k;
    int d = d0 + tx;
    if(j < LQ_) Qtb[(size_t)j*D_ + d] = t[tx][ty+8*k];
  }
}

// ---------------- K1: S[b,i,j] = sum_d (w1+w3*Ct)[i,d]*Q[d,j] + t2[i] ----------------
__global__ __launch_bounds__(256) void k_S(const float* __restrict__ Q,
                                           const float* __restrict__ W,
                                           const float* __restrict__ Ct,
                                           float* __restrict__ S){
  __shared__ float Qs[32][132];
  __shared__ float Vs[32][68];    // [dc][il] transposed: inner loop reads b128
  __shared__ float t2s[64];
  int b   = blockIdx.y;
  int i0  = blockIdx.x * 64;
  int tid = threadIdx.x;
  const float* Wb  = W  + (size_t)b * LC_ * 384;
  const float* Ctb = Ct + (size_t)b * LC_ * D_;
  const float* Qb  = Q  + (size_t)b * D_ * LQ_;

  // t2[i] = sum_d w2[i,d]*Ct[i,d]
  {
    int g = tid >> 5, l = tid & 31;
    for(int rep=0; rep<8; rep++){
      int il = rep*8 + g;
      int i  = i0 + il;
      float s = 0.f;
      if(i < LC_){
        const float* wrow  = Wb  + (size_t)i*384 + 128;
        const float* ctrow = Ctb + (size_t)i*D_;
#pragma unroll
        for(int k=0;k<4;k++){ int d = l + 32*k; s += wrow[d]*ctrow[d]; }
      }
#pragma unroll
      for(int m=16;m>0;m>>=1) s += __shfl_xor(s, m, 64);
      if(l==0) t2s[il] = s;
    }
  }

  int jt = tid & 15;
  int ti = tid >> 4;
  float acc[4][8] = {};

  for(int c=0;c<4;c++){
    int dc0 = c*32;
    __syncthreads();
    for(int idx=tid; idx<32*128; idx+=256){
      int dc = idx >> 7, j = idx & 127;
      Qs[dc][j] = (j < LQ_) ? Qb[(size_t)(dc0+dc)*LQ_ + j] : 0.f;
    }
    for(int idx=tid; idx<64*32; idx+=256){
      int il = idx >> 5, dc = idx & 31;
      int i = i0 + il;
      float v = 0.f;
      if(i < LC_){
        const float* wrow = Wb + (size_t)i*384;
        float ct = Ctb[(size_t)i*D_ + dc0+dc];
        v = wrow[dc0+dc] + wrow[256+dc0+dc]*ct;
      }
      Vs[dc][il] = v;
    }
    __syncthreads();
#pragma unroll 4
    for(int dc=0; dc<32; dc++){
      float4 vv = *(const float4*)&Vs[dc][ti*4];
      float v[4] = {vv.x, vv.y, vv.z, vv.w};
      float4 q0 = *(const float4*)&Qs[dc][jt*8];
      float4 q1 = *(const float4*)&Qs[dc][jt*8+4];
      float q[8] = {q0.x,q0.y,q0.z,q0.w,q1.x,q1.y,q1.z,q1.w};
#pragma unroll
      for(int ii=0; ii<4; ii++)
#pragma unroll
        for(int jj=0; jj<8; jj++) acc[ii][jj] += v[ii]*q[jj];
    }
  }
  float* Sb = S + (size_t)b * LC_ * SP;
#pragma unroll
  for(int ii=0; ii<4; ii++){
    int il = ti*4+ii;
    int i  = i0 + il;
    if(i < LC_){
      float t2v = t2s[il];
      float4 o0, o1;
      o0.x=acc[ii][0]+t2v; o0.y=acc[ii][1]+t2v; o0.z=acc[ii][2]+t2v; o0.w=acc[ii][3]+t2v;
      o1.x=acc[ii][4]+t2v; o1.y=acc[ii][5]+t2v; o1.z=acc[ii][6]+t2v; o1.w=acc[ii][7]+t2v;
      if(jt*8   < SP) *(float4*)&Sb[(size_t)i*SP + jt*8    ] = o0;  // j<104 only
      if(jt*8+4 < SP) *(float4*)&Sb[(size_t)i*SP + jt*8 + 4] = o1;
    }
  }
}

// ---------------- K2a: partial column stats (softmax axis=1) ----------------
#define NIC 8
__global__ __launch_bounds__(256) void k_colstats1(const float* __restrict__ S,
                                                   float* __restrict__ pm,
                                                   float* __restrict__ ps){
  __shared__ float lm[8][128], lsum[8][128];
  int b = blockIdx.x, ic = blockIdx.y;
  int tid = threadIdx.x;
  int jt = tid & 31, h = tid >> 5;
  int j0 = jt*4;
  int ni = min(16, 125 - h*16);
  const float* Sb = S + (size_t)b * LC_ * SP;
  float m[4] = {-1e30f,-1e30f,-1e30f,-1e30f}, s[4] = {0.f,0.f,0.f,0.f};
  if(jt < 26){
    for(int r=0;r<ni;r++){
      int i = ic*125 + h*16 + r;
      float4 x = *(const float4*)&Sb[(size_t)i*SP + j0];
      float xv[4] = {x.x,x.y,x.z,x.w};
#pragma unroll
      for(int k=0;k<4;k++){
        if(xv[k] > m[k]){ s[k] = s[k]*__expf(m[k]-xv[k]) + 1.f; m[k] = xv[k]; }
        else              s[k] += __expf(xv[k]-m[k]);
      }
    }
  }
#pragma unroll
  for(int k=0;k<4;k++){
    int j = j0+k;
    if(j < 128){ lm[h][j] = m[k]; lsum[h][j] = s[k]; }
  }
  __syncthreads();
  if(tid < 128){
    float mm = -1e30f, ss = 0.f;
#pragma unroll
    for(int hh=0; hh<8; hh++){
      float m2 = lm[hh][tid], s2 = lsum[hh][tid];
      if(m2 > mm){ ss = ss*__expf(mm-m2) + s2; mm = m2; }
      else         ss += s2*__expf(m2-mm);
    }
    pm[((size_t)b*NIC + ic)*128 + tid] = mm;
    ps[((size_t)b*NIC + ic)*128 + tid] = ss;
  }
}

// ---------------- K2b: combine partials ----------------
__global__ __launch_bounds__(128) void k_colstats2(const float* __restrict__ pm,
                                                   const float* __restrict__ ps,
                                                   float* __restrict__ cm,
                                                   float* __restrict__ cs){
  int b = blockIdx.x, j = threadIdx.x;
  float mm = -1e30f, ss = 0.f;
#pragma unroll
  for(int ic=0; ic<NIC; ic++){
    float m2 = pm[((size_t)b*NIC + ic)*128 + j];
    float s2 = ps[((size_t)b*NIC + ic)*128 + j];
    if(m2 > mm){ ss = ss*__expf(mm-m2) + s2; mm = m2; }
    else         ss += s2*__expf(m2-mm);
  }
  cm[b*JP + j] = mm;
  cs[b*JP + j] = (ss == 0.f) ? 1.f : ss;
}

// ---------------- K3: M[b,j,d] = sum_i softmax_col(S)[i,j]*Ct[i,d] ----------------
#define MJQ 25
__global__ __launch_bounds__(1024) void k_Mj(const float* __restrict__ S,
                                             const float* __restrict__ Ct,
                                             const float* __restrict__ cm_,
                                             const float* __restrict__ cs_,
                                             float* __restrict__ M){
  __shared__ float Es[4][16][32];    // [grp][i-chunk][j_local]
  __shared__ float Cs[4][16][132];   // [grp][i-chunk][d]
  __shared__ float Macc[25][132];    // cross-group accumulation tile
  __shared__ float cml[32], icsl[32];
  int b  = blockIdx.x;
  int jq = blockIdx.y;
  int j0 = jq * MJQ;
  int tid = threadIdx.x;             // 0..1023
  int grp = tid >> 8;                // 0..3 (i-range group)
  int t   = tid & 255;
  if(tid < 32){
    int j = j0 + tid;
    cml[tid]  = (tid < MJQ && j < LQ_) ? cm_[b*JP + j] : 0.f;
    icsl[tid] = (tid < MJQ && j < LQ_) ? 1.f/cs_[b*JP + j] : 0.f;
  }
  __syncthreads();
  int dt = t & 31;   // d = dt*4 + dd
  int jt = t >> 5;   // j_local = jt*4 + jj (0..31, mask < MJQ)
  float acc[4][4] = {};
  const float* Sb  = S  + (size_t)b * LC_ * SP + j0;
  const float* Ctb = Ct + (size_t)b * LC_ * D_;
  int ibase = grp * 250;

  for(int i0=0; i0<250; i0+=16){
    int rem = min(16, 250 - i0);
    __syncthreads();
    for(int idx=t; idx<16*32; idx+=256){
      int ii = idx >> 5, jl = idx & 31;
      float e = 0.f;
      if(ii < rem && jl < MJQ)
        e = __expf(Sb[(size_t)(ibase+i0+ii)*SP + jl] - cml[jl]);
      Es[grp][ii][jl] = e;
    }
    for(int idx=t; idx<16*32; idx+=256){
      int ii = idx >> 5, f = idx & 31;
      float4 v = make_float4(0.f,0.f,0.f,0.f);
      if(ii < rem) v = *(const float4*)&Ctb[(size_t)(ibase+i0+ii)*D_ + f*4];
      *(float4*)&Cs[grp][ii][f*4] = v;
    }
    __syncthreads();
#pragma unroll
    for(int ii=0; ii<16; ii++){
      float4 e4 = *(const float4*)&Es[grp][ii][jt*4];
      float4 c4 = *(const float4*)&Cs[grp][ii][dt*4];
      float e[4] = {e4.x,e4.y,e4.z,e4.w};
      float c[4] = {c4.x,c4.y,c4.z,c4.w};
#pragma unroll
      for(int jj=0; jj<4; jj++)
#pragma unroll
        for(int dd=0; dd<4; dd++) acc[jj][dd] += e[jj]*c[dd];
    }
  }

  // cross-group reduce (turn-taking; deterministic)
  for(int g=0; g<4; g++){
    if(grp == g){
#pragma unroll
      for(int jj=0; jj<4; jj++){
        int jl = jt*4 + jj;
        if(jl < MJQ){
#pragma unroll
          for(int dd=0; dd<4; dd++){
            if(g == 0) Macc[jl][dt*4+dd]  = acc[jj][dd];
            else       Macc[jl][dt*4+dd] += acc[jj][dd];
          }
        }
      }
    }
    __syncthreads();
  }
  if(grp == 0){
    float* Mb = M + (size_t)b * JP * D_;
#pragma unroll
    for(int jj=0; jj<4; jj++){
      int jl = jt*4 + jj;
      if(jl < MJQ && (j0+jl) < LQ_){
        float ics = icsl[jl];
        float4 o;
        o.x = Macc[jl][dt*4+0]*ics; o.y = Macc[jl][dt*4+1]*ics;
        o.z = Macc[jl][dt*4+2]*ics; o.w = Macc[jl][dt*4+3]*ics;
        *(float4*)&Mb[(size_t)(j0+jl)*D_ + dt*4] = o;
      }
    }
  }
}

// ---------------- K4: row softmax + A=S1@Qt + Bm=S1@M + assemble output ----------------
// 512 threads, 128-i tile (was 256/64): 2x work per barrier, half the blocks,
// 2 blocks/CU x 8 waves = 16 waves/CU. R7's reg-pipelining reverted (regressed).
__global__ __launch_bounds__(512) void k_final(const float* __restrict__ S,
                                               const float* __restrict__ Qt,
                                               const float* __restrict__ M,
                                               const float* __restrict__ C,
                                               float* __restrict__ out){
  __shared__ float lds[17536];
  float* S1s = lds;            // [128][104] = 13312
  float* Qc  = lds + 13312;    // [16][132]  = 2112
  float* Mc  = lds + 15424;    // [16][132]  = 2112
  float* At  = lds;            // [128][133] = 17024 epilogue transpose (aliases all)
  int b   = blockIdx.y;
  int i0  = blockIdx.x * 128;
  int tid = threadIdx.x;
  const float* Sb  = S  + (size_t)b * LC_ * SP;
  const float* Qtb = Qt + (size_t)b * LQ_ * D_;
  const float* Mb  = M  + (size_t)b * JP * D_;

  // stage S tile (zero cols 100..103)
  for(int idx=tid; idx<128*26; idx+=512){
    int il = idx / 26, f = idx % 26;
    int i = i0 + il;
    float4 v = make_float4(0.f,0.f,0.f,0.f);
    if(i < LC_ && f < 25) v = *(const float4*)&Sb[(size_t)i*SP + f*4];
    *(float4*)&S1s[il*104 + f*4] = v;
  }
  __syncthreads();

  // in-LDS row softmax over j<100 (8 waves x 16 rows, 2 cols/lane)
  {
    int w = tid >> 6, l = tid & 63;
    for(int r=0; r<16; r++){
      int il = w*16 + r;
      float x0 = (2*l   < LQ_) ? S1s[il*104 + 2*l  ] : -1e30f;
      float x1 = (2*l+1 < LQ_) ? S1s[il*104 + 2*l+1] : -1e30f;
      float m = fmaxf(x0,x1);
#pragma unroll
      for(int mm=32;mm>0;mm>>=1) m = fmaxf(m, __shfl_xor(m, mm, 64));
      float e0 = (2*l   < LQ_) ? __expf(x0-m) : 0.f;
      float e1 = (2*l+1 < LQ_) ? __expf(x1-m) : 0.f;
      float s = e0+e1;
#pragma unroll
      for(int mm=32;mm>0;mm>>=1) s += __shfl_xor(s, mm, 64);
      float inv = 1.f/s;
      if(2*l   < LQ_) S1s[il*104 + 2*l  ] = e0*inv;
      if(2*l+1 < LQ_) S1s[il*104 + 2*l+1] = e1*inv;
    }
  }

  // dual GEMM, K chunked by 16 j; thread tile 8i x 4d
  int dt = tid & 31;   // d = dt*4 + dd
  int it = tid >> 5;   // i_local = it*8 + ii  (0..15 -> 128 rows)
  float A[8][4] = {}, Bm[8][4] = {};
  for(int j0=0; j0<LQ_; j0+=16){
    int nj = min(16, LQ_-j0);
    __syncthreads();
    for(int idx=tid; idx<nj*32; idx+=512){
      int jj = idx >> 5, f = idx & 31;
      *(float4*)&Qc[jj*132 + f*4] = *(const float4*)&Qtb[(size_t)(j0+jj)*D_ + f*4];
      *(float4*)&Mc[jj*132 + f*4] = *(const float4*)&Mb [(size_t)(j0+jj)*D_ + f*4];
    }
    __syncthreads();
    for(int jj4=0; jj4<nj; jj4+=4){
      float4 sv[8], qv[4], mv[4];
#pragma unroll
      for(int ii=0; ii<8; ii++) sv[ii] = *(const float4*)&S1s[(it*8+ii)*104 + j0+jj4];
#pragma unroll
      for(int jj=0; jj<4; jj++){
        qv[jj] = *(const float4*)&Qc[(jj4+jj)*132 + dt*4];
        mv[jj] = *(const float4*)&Mc[(jj4+jj)*132 + dt*4];
      }
#pragma unroll
      for(int ii=0; ii<8; ii++){
        float sf[4] = {sv[ii].x, sv[ii].y, sv[ii].z, sv[ii].w};
#pragma unroll
        for(int jj=0; jj<4; jj++){
          A[ii][0]  += sf[jj]*qv[jj].x; A[ii][1]  += sf[jj]*qv[jj].y;
          A[ii][2]  += sf[jj]*qv[jj].z; A[ii][3]  += sf[jj]*qv[jj].w;
          Bm[ii][0] += sf[jj]*mv[jj].x; Bm[ii][1] += sf[jj]*mv[jj].y;
          Bm[ii][2] += sf[jj]*mv[jj].z; Bm[ii][3] += sf[jj]*mv[jj].w;
        }
      }
    }
  }

  // epilogue: two LDS round-trips (A then Bm), stride 133 -> 2-way-free reads
  const float* Cb = C + (size_t)b * D_ * LC_;
  float* ob = out + (size_t)b * 512 * LC_;
  int il2 = tid & 127, dg = tid >> 7;   // dg 0..3, d = dg*32 + dd2
  int i = i0 + il2;

  __syncthreads();
#pragma unroll
  for(int ii=0; ii<8; ii++)
#pragma unroll
    for(int dd=0; dd<4; dd++) At[(it*8+ii)*133 + dt*4+dd] = A[ii][dd];
  __syncthreads();
  if(i < LC_){
    for(int dd2=0; dd2<32; dd2++){
      int d = dg*32 + dd2;
      float a = At[il2*133 + d];
      float c = Cb[(size_t)d*LC_ + i];
      ob[(size_t)d*LC_ + i]       = c;
      ob[(size_t)(128+d)*LC_ + i] = a;
      ob[(size_t)(256+d)*LC_ + i] = c*a;
    }
  }
  __syncthreads();
#pragma unroll
  for(int ii=0; ii<8; ii++)
#pragma unroll
    for(int dd=0; dd<4; dd++) At[(it*8+ii)*133 + dt*4+dd] = Bm[ii][dd];
  __syncthreads();
  if(i < LC_){
    for(int dd2=0; dd2<32; dd2++){
      int d = dg*32 + dd2;
      float bm = At[il2*133 + d];
      float c  = Cb[(size_t)d*LC_ + i];
      ob[(size_t)(384+d)*LC_ + i] = c*bm;
    }
  }
}

extern "C" void kernel_launch(void* const* d_in, const int* in_sizes, int n_in,
                              void* d_out, int out_size, void* d_ws, size_t ws_size,
                              hipStream_t stream){
  const float* C = (const float*)d_in[0];
  const float* Q = (const float*)d_in[1];
  const float* W = (const float*)d_in[2];
  float* out = (float*)d_out;
  float* ws  = (float*)d_ws;
  // ws layout (floats): S 6.656M | Ct 8.192M | M 1.049M | Qt 0.819M | pm/ps 65.5K*2 | cm/cs 8.2K*2 = 67.5 MB
  float* S  = ws;
  float* Ct = ws + 6656000;
  float* M  = ws + 14848000;
  float* Qt = ws + 15896576;
  float* pm = ws + 16715776;
  float* ps = ws + 16781312;
  float* cm = ws + 16846848;
  float* cs = ws + 16855040;

  k_transpose <<<dim3(32,4,64), dim3(32,8), 0, stream>>>(C, Ct);
  k_transposeQ<<<dim3(4,4,64),  dim3(32,8), 0, stream>>>(Q, Qt);
  k_S         <<<dim3(16,64),   256, 0, stream>>>(Q, W, Ct, S);
  k_colstats1 <<<dim3(64,NIC),  256, 0, stream>>>(S, pm, ps);
  k_colstats2 <<<64,            128, 0, stream>>>(pm, ps, cm, cs);
  k_Mj        <<<dim3(64,4),    1024, 0, stream>>>(S, Ct, cm, cs, M);
  k_final     <<<dim3(8,64),    512, 0, stream>>>(S, Qt, M, C, out);
}